// Round 1
// baseline (642.305 us; speedup 1.0000x reference)
//
#include <hip/hip_runtime.h>

#define BATCH 2048
#define DIM   1024
#define SPC   8
#define BM    128
#define BK    32
#define NKT   (DIM / BK)   // 32

constexpr float INV_T = 1.0f / 0.01f;   // compile-time fp32, matches x/temp to 1ulp

__device__ __forceinline__ float sig_main(float x) {
  // faithful to reference: e = clip(-x/0.01, -50, 50); 1/(1+exp(e))
  float e = -x * INV_T;
  e = fminf(fmaxf(e, -50.0f), 50.0f);
  return 1.0f / (1.0f + __expf(e));
}

// ---------------- kernel 1: G[q][i] = <preds[q], preds[group(q)*8+i]> ----------------
__global__ __launch_bounds__(256) void k_group_sims(const float* __restrict__ preds,
                                                    float* __restrict__ G) {
  __shared__ float rows[SPC][DIM + 4];   // +4 pad: row stride 1028 -> bank shift 4/row
  __shared__ float part[64][4];
  const int g = blockIdx.x;
  const int tid = threadIdx.x;
  const float4* src = (const float4*)(preds + (size_t)g * SPC * DIM);
#pragma unroll
  for (int c = 0; c < 8; ++c) {
    int idx = c * 256 + tid;          // float4 index over [8][256]
    float4 v = src[idx];
    int row = idx >> 8;
    int col4 = idx & 255;
    *(float4*)&rows[row][col4 << 2] = v;
  }
  __syncthreads();
  const int p  = tid & 63;            // pair id 0..63
  const int sl = tid >> 6;            // K-slice 0..3 (256 elems each)
  const int qi = p >> 3, mi = p & 7;
  const float4* ra = (const float4*)&rows[qi][sl * 256];
  const float4* rb = (const float4*)&rows[mi][sl * 256];
  float s = 0.0f;
#pragma unroll 8
  for (int e = 0; e < 64; ++e) {
    float4 a = ra[e], b = rb[e];
    s += a.x * b.x + a.y * b.y + a.z * b.z + a.w * b.w;
  }
  part[p][sl] = s;
  __syncthreads();
  if (tid < 64) {
    float v = part[tid][0] + part[tid][1] + part[tid][2] + part[tid][3];
    G[(size_t)(g * SPC + (tid >> 3)) * SPC + (tid & 7)] = v;
  }
}

// ---------------- kernel 2: fused S-tile GEMM + sigmoid rank accumulation ----------------
// rk_sum[q][i] += sum_{j in tile} sig(S[q,j] - G[q,i])   (diag j==g(q)*8+i excluded)
__global__ __launch_bounds__(256) void k_main(const float* __restrict__ preds,
                                              const float* __restrict__ G,
                                              float* __restrict__ rk_sum) {
  __shared__ float As[2][BM][BK];   // 32 KB
  __shared__ float Bs[2][BM][BK];   // 32 KB
  const int tid = threadIdx.x;
  const int tx = tid & 15;          // j direction (16)
  const int ty = tid >> 4;          // q direction (16)
  const int qbase = blockIdx.y * BM;
  const int jbase = blockIdx.x * BM;

  float acc[8][8];
#pragma unroll
  for (int a = 0; a < 8; ++a)
#pragma unroll
    for (int b = 0; b < 8; ++b) acc[a][b] = 0.0f;

  float4 ra[4], rb[4];
  const int srow = tid >> 3;        // staging row 0..31 (+32c)
  const int sk4  = tid & 7;         // staging float4-column within BK

  auto LOAD = [&](int kt) {         // global -> regs (coalesced 128B/row segments)
    const int kk = kt * BK + (sk4 << 2);
#pragma unroll
    for (int c = 0; c < 4; ++c) {
      const int row = srow + (c << 5);
      ra[c] = *(const float4*)(preds + (size_t)(qbase + row) * DIM + kk);
      rb[c] = *(const float4*)(preds + (size_t)(jbase + row) * DIM + kk);
    }
  };
  auto STORE = [&](int nb) {        // regs -> LDS at XOR-swizzled slot
#pragma unroll
    for (int c = 0; c < 4; ++c) {
      const int row = srow + (c << 5);
      const int sl = (sk4 ^ ((row >> 3) & 7)) << 2;
      *(float4*)&As[nb][row][sl] = ra[c];
      *(float4*)&Bs[nb][row][sl] = rb[c];
    }
  };

  LOAD(0);
  STORE(0);
  __syncthreads();
  int buf = 0;
#pragma unroll 1
  for (int kt = 0; kt < NKT; ++kt) {
    if (kt + 1 < NKT) LOAD(kt + 1);          // issue early; hides under 2048 FMAs
#pragma unroll
    for (int k4 = 0; k4 < 8; ++k4) {
      const int sa = (k4 ^ (ty & 7)) << 2;   // read back through the same XOR
      const int sb = (k4 ^ (tx & 7)) << 2;
      float4 af[8], bf[8];
#pragma unroll
      for (int a = 0; a < 8; ++a) af[a] = *(const float4*)&As[buf][ty * 8 + a][sa];
#pragma unroll
      for (int b = 0; b < 8; ++b) bf[b] = *(const float4*)&Bs[buf][tx * 8 + b][sb];
#pragma unroll
      for (int a = 0; a < 8; ++a)
#pragma unroll
        for (int b = 0; b < 8; ++b) {
          acc[a][b] += af[a].x * bf[b].x;
          acc[a][b] += af[a].y * bf[b].y;
          acc[a][b] += af[a].z * bf[b].z;
          acc[a][b] += af[a].w * bf[b].w;
        }
    }
    if (kt + 1 < NKT) STORE(buf ^ 1);        // write-late after compute (T14)
    __syncthreads();
    buf ^= 1;
  }

  // ---- fused epilogue: 8 sigmoids per S value, reduce over tile's j-range ----
  const int lane = tid & 63;
  const bool sameGroup = (qbase + ty * 8) == (jbase + tx * 8);  // q-group == j-group
#pragma unroll
  for (int a = 0; a < 8; ++a) {
    const int q = qbase + ty * 8 + a;
    const float4 g0 = *(const float4*)&G[(size_t)q * 8];
    const float4 g1 = *(const float4*)&G[(size_t)q * 8 + 4];
    const float gv[8] = {g0.x, g0.y, g0.z, g0.w, g1.x, g1.y, g1.z, g1.w};
#pragma unroll
    for (int i = 0; i < 8; ++i) {
      float p = 0.0f;
#pragma unroll
      for (int b = 0; b < 8; ++b) {
        float v = sig_main(acc[a][b] - gv[i]);
        if (sameGroup && i == b) v = 0.0f;   // exact diag exclusion j == g(q)*8+i
        p += v;
      }
      // reduce across the 16 j-lanes (tx) sharing this q
      p += __shfl_xor(p, 1);
      p += __shfl_xor(p, 2);
      p += __shfl_xor(p, 4);
      p += __shfl_xor(p, 8);
      if ((lane & 15) == 0) atomicAdd(&rk_sum[(size_t)q * 8 + i], p);
    }
  }
}

// ---------------- kernel 3: rank -> recall -> scalar loss ----------------
__global__ __launch_bounds__(256) void k_fin(const float* __restrict__ rk_sum,
                                             float* __restrict__ out) {
  const int q = blockIdx.x * 256 + threadIdx.x;
  const float kv[5]  = {1.f, 2.f, 4.f, 8.f, 16.f};
  const float rkt[5] = {1.f, 0.5f, 0.25f, 0.125f, 0.0625f};  // 1/kt, exact pow2
  const float nv[5]  = {1.f, 2.f, 4.f, 7.f, 7.f};            // min(k, spc-1)
  const int r = q & 7;
  float vs[5] = {0.f, 0.f, 0.f, 0.f, 0.f};
#pragma unroll
  for (int i = 0; i < 8; ++i) {
    const float rk = 1.0f + rk_sum[(size_t)q * 8 + i];
    const bool self = (i == r);
#pragma unroll
    for (int k = 0; k < 5; ++k) {
      float e = (rk - kv[k]) * rkt[k];       // = clip(-(kv-rk)/kt, ...)
      e = fminf(fmaxf(e, -50.0f), 50.0f);
      float v = 1.0f / (1.0f + __expf(e));
      vs[k] += self ? 0.0f : v;
    }
  }
  float rq = 0.0f;
#pragma unroll
  for (int k = 0; k < 5; ++k) rq += fminf(vs[k], kv[k]) / nv[k];
  float t = (1.0f - rq * 0.2f) * (1.0f / (float)BATCH);
#pragma unroll
  for (int o = 1; o < 64; o <<= 1) t += __shfl_xor(t, o);
  if ((threadIdx.x & 63) == 0) atomicAdd(out, t);
}

extern "C" void kernel_launch(void* const* d_in, const int* in_sizes, int n_in,
                              void* d_out, int out_size, void* d_ws, size_t ws_size,
                              hipStream_t stream) {
  const float* preds = (const float*)d_in[0];
  // d_in[1] (q_idx) is unused by the reference computation.
  float* G      = (float*)d_ws;                    // 2048*8 floats = 64 KB
  float* rk_sum = (float*)d_ws + BATCH * SPC;      // 2048*8 floats = 64 KB
  hipMemsetAsync(rk_sum, 0, (size_t)BATCH * SPC * sizeof(float), stream);
  hipMemsetAsync(d_out, 0, sizeof(float), stream);
  k_group_sims<<<BATCH / SPC, 256, 0, stream>>>(preds, G);
  k_main<<<dim3(BATCH / BM, BATCH / BM), 256, 0, stream>>>(preds, G, rk_sum);
  k_fin<<<BATCH / 256, 256, 0, stream>>>(rk_sum, (float*)d_out);
}

// Round 2
// 197.895 us; speedup vs baseline: 3.2457x; 3.2457x over previous
//
#include <hip/hip_runtime.h>

#define BATCH 2048
#define DIM   1024
#define SPC   8

typedef _Float16 half8  __attribute__((ext_vector_type(8)));
typedef _Float16 half4v __attribute__((ext_vector_type(4)));
typedef float    f32x4  __attribute__((ext_vector_type(4)));

constexpr float INV_T = 1.0f / 0.01f;   // same compile-time constant as the passing R1 kernel

__device__ __forceinline__ float sig_main(float x) {
  // faithful: e = clip(-x/0.01, -50, 50); 1/(1+exp(e))
  float e = -x * INV_T;
  e = fminf(fmaxf(e, -50.0f), 50.0f);
  return 1.0f / (1.0f + __expf(e));
}

__device__ __forceinline__ void gl_lds16(const _Float16* g, _Float16* l) {
  __builtin_amdgcn_global_load_lds((const __attribute__((address_space(1))) void*)g,
                                   (__attribute__((address_space(3))) void*)l, 16, 0, 0);
}

// ---------------- kernel 0: fp32 -> fp16 hi/lo split ----------------
__global__ __launch_bounds__(256) void k_prep(const float* __restrict__ p,
                                              _Float16* __restrict__ Ph,
                                              _Float16* __restrict__ Pl) {
  const int i = blockIdx.x * 256 + threadIdx.x;       // float4 index
  const float4 x = ((const float4*)p)[i];
  half4v h, l;
  h[0] = (_Float16)x.x; l[0] = (_Float16)(x.x - (float)h[0]);
  h[1] = (_Float16)x.y; l[1] = (_Float16)(x.y - (float)h[1]);
  h[2] = (_Float16)x.z; l[2] = (_Float16)(x.z - (float)h[2]);
  h[3] = (_Float16)x.w; l[3] = (_Float16)(x.w - (float)h[3]);
  ((half4v*)Ph)[i] = h;
  ((half4v*)Pl)[i] = l;
}

// ---------------- kernel 1: G[q][i] = <preds[q], preds[group(q)*8+i]> (exact fp32) ----------------
__global__ __launch_bounds__(256) void k_group_sims(const float* __restrict__ preds,
                                                    float* __restrict__ G) {
  __shared__ float rows[SPC][DIM + 4];
  __shared__ float part[64][4];
  const int g = blockIdx.x;
  const int tid = threadIdx.x;
  const float4* src = (const float4*)(preds + (size_t)g * SPC * DIM);
#pragma unroll
  for (int c = 0; c < 8; ++c) {
    int idx = c * 256 + tid;
    float4 v = src[idx];
    int row = idx >> 8;
    int col4 = idx & 255;
    *(float4*)&rows[row][col4 << 2] = v;
  }
  __syncthreads();
  const int p  = tid & 63;
  const int sl = tid >> 6;
  const int qi = p >> 3, mi = p & 7;
  const float4* ra = (const float4*)&rows[qi][sl * 256];
  const float4* rb = (const float4*)&rows[mi][sl * 256];
  float s = 0.0f;
#pragma unroll 8
  for (int e = 0; e < 64; ++e) {
    float4 a = ra[e], b = rb[e];
    s += a.x * b.x + a.y * b.y + a.z * b.z + a.w * b.w;
  }
  part[p][sl] = s;
  __syncthreads();
  if (tid < 64) {
    float v = part[tid][0] + part[tid][1] + part[tid][2] + part[tid][3];
    G[(size_t)(g * SPC + (tid >> 3)) * SPC + (tid & 7)] = v;
  }
}

// ---------------- kernel 2: MFMA split-fp16 S-tile GEMM + fused sigmoid-rank epilogue ----------------
// S = Ah*Bh + Ah*Bl + Al*Bh (P @ P^T); rk_sum[q][i] += sum_j sig(S[q,j]-G[q,i]), diag j==g(q)*8+i excluded.
__global__ __launch_bounds__(256, 1) void k_main(const _Float16* __restrict__ Ph,
                                                 const _Float16* __restrict__ Pl,
                                                 const float* __restrict__ G,
                                                 float* __restrict__ rk_sum) {
  __shared__ __align__(16) _Float16 sAh[2][128 * 32];   // 8 KB each buffer
  __shared__ __align__(16) _Float16 sAl[2][128 * 32];
  __shared__ __align__(16) _Float16 sBh[2][128 * 32];
  __shared__ __align__(16) _Float16 sBl[2][128 * 32];   // total 64 KB
  const int t    = threadIdx.x;
  const int lane = t & 63;
  const int w    = t >> 6;
  const int wr   = w >> 1, wc = w & 1;                  // 2x2 wave grid, 64x64 per wave
  const int qb = blockIdx.y * 128, jb = blockIdx.x * 128;

  f32x4 acc[4][4];
#pragma unroll
  for (int m = 0; m < 4; ++m)
#pragma unroll
    for (int n = 0; n < 4; ++n) acc[m][n] = (f32x4){0.f, 0.f, 0.f, 0.f};

  // 8 global_load_lds(16B) per thread per tile: linear LDS [row][k], wave-uniform base + lane*16
  auto STAGE = [&](int b, int kt) {
#pragma unroll
    for (int e = 0; e < 2; ++e) {
      const int slot = e * 256 + t;                     // 16B slot = row*4 + k4chunk
      const int row  = slot >> 2;
      const int kofs = kt * 32 + (slot & 3) * 8;
      const size_t ga = (size_t)(qb + row) * DIM + kofs;
      const size_t gb = (size_t)(jb + row) * DIM + kofs;
      gl_lds16(Ph + ga, &sAh[b][slot * 8]);
      gl_lds16(Pl + ga, &sAl[b][slot * 8]);
      gl_lds16(Ph + gb, &sBh[b][slot * 8]);
      gl_lds16(Pl + gb, &sBl[b][slot * 8]);
    }
  };

  STAGE(0, 0);
  __syncthreads();
#pragma unroll 1
  for (int kt = 0; kt < DIM / 32; ++kt) {
    const int b = kt & 1;
    if (kt + 1 < DIM / 32) STAGE(b ^ 1, kt + 1);        // prefetch next tile (in flight across compute)
    const int rA = wr * 64 + (lane & 15);
    const int cB = wc * 64 + (lane & 15);
    const int kc = (lane >> 4) * 8;                     // k-chunk; any bijection cancels (A,B loaded identically)
    half8 ah[4], al[4], bh[4], bl[4];
#pragma unroll
    for (int m = 0; m < 4; ++m) {
      ah[m] = *(const half8*)&sAh[b][(rA + m * 16) * 32 + kc];
      al[m] = *(const half8*)&sAl[b][(rA + m * 16) * 32 + kc];
    }
#pragma unroll
    for (int n = 0; n < 4; ++n) {
      bh[n] = *(const half8*)&sBh[b][(cB + n * 16) * 32 + kc];
      bl[n] = *(const half8*)&sBl[b][(cB + n * 16) * 32 + kc];
    }
#pragma unroll
    for (int m = 0; m < 4; ++m)
#pragma unroll
      for (int n = 0; n < 4; ++n) {
        acc[m][n] = __builtin_amdgcn_mfma_f32_16x16x32_f16(ah[m], bh[n], acc[m][n], 0, 0, 0);
        acc[m][n] = __builtin_amdgcn_mfma_f32_16x16x32_f16(ah[m], bl[n], acc[m][n], 0, 0, 0);
        acc[m][n] = __builtin_amdgcn_mfma_f32_16x16x32_f16(al[m], bh[n], acc[m][n], 0, 0, 0);
      }
    __syncthreads();
  }

  // ---- fused epilogue; C/D layout (HW-verified): col=lane&15, row=(lane>>4)*4+reg ----
  const int colLane = lane & 15;
#pragma unroll
  for (int m = 0; m < 4; ++m) {
#pragma unroll
    for (int v = 0; v < 4; ++v) {
      const int q = qb + wr * 64 + m * 16 + (lane >> 4) * 4 + v;
      const float4 g0 = *(const float4*)&G[(size_t)q * 8];
      const float4 g1 = *(const float4*)&G[(size_t)q * 8 + 4];
      const float gv[8] = {g0.x, g0.y, g0.z, g0.w, g1.x, g1.y, g1.z, g1.w};
      const int qg = q >> 3;
#pragma unroll
      for (int i = 0; i < 8; ++i) {
        float p = 0.0f;
#pragma unroll
        for (int n = 0; n < 4; ++n) {
          const int j = jb + wc * 64 + n * 16 + colLane;
          float s = sig_main(acc[m][n][v] - gv[i]);
          if ((j >> 3) == qg && (j & 7) == i) s = 0.0f;  // exact diag exclusion
          p += s;
        }
        p += __shfl_xor(p, 1);                           // reduce the 16 j-lanes
        p += __shfl_xor(p, 2);
        p += __shfl_xor(p, 4);
        p += __shfl_xor(p, 8);
        if (colLane == 0) atomicAdd(&rk_sum[(size_t)q * 8 + i], p);
      }
    }
  }
}

// ---------------- kernel 3: rank -> recall -> scalar loss ----------------
__global__ __launch_bounds__(256) void k_fin(const float* __restrict__ rk_sum,
                                             float* __restrict__ out) {
  const int q = blockIdx.x * 256 + threadIdx.x;
  const float kv[5]  = {1.f, 2.f, 4.f, 8.f, 16.f};
  const float rkt[5] = {1.f, 0.5f, 0.25f, 0.125f, 0.0625f};  // 1/kt, exact pow2
  const float nv[5]  = {1.f, 2.f, 4.f, 7.f, 7.f};            // min(k, spc-1)
  const int r = q & 7;
  float vs[5] = {0.f, 0.f, 0.f, 0.f, 0.f};
#pragma unroll
  for (int i = 0; i < 8; ++i) {
    const float rk = 1.0f + rk_sum[(size_t)q * 8 + i];
    const bool self = (i == r);
#pragma unroll
    for (int k = 0; k < 5; ++k) {
      float e = (rk - kv[k]) * rkt[k];
      e = fminf(fmaxf(e, -50.0f), 50.0f);
      float v = 1.0f / (1.0f + __expf(e));
      vs[k] += self ? 0.0f : v;
    }
  }
  float rq = 0.0f;
#pragma unroll
  for (int k = 0; k < 5; ++k) rq += fminf(vs[k], kv[k]) / nv[k];
  float tv = (1.0f - rq * 0.2f) * (1.0f / (float)BATCH);
#pragma unroll
  for (int o = 1; o < 64; o <<= 1) tv += __shfl_xor(tv, o);
  if ((threadIdx.x & 63) == 0) atomicAdd(out, tv);
}

extern "C" void kernel_launch(void* const* d_in, const int* in_sizes, int n_in,
                              void* d_out, int out_size, void* d_ws, size_t ws_size,
                              hipStream_t stream) {
  const float* preds = (const float*)d_in[0];
  float* G      = (float*)d_ws;                               // 64 KB
  float* rk_sum = (float*)d_ws + (size_t)BATCH * SPC;         // 64 KB
  _Float16* Ph  = (_Float16*)((char*)d_ws + (128 << 10));     // 4 MB
  _Float16* Pl  = Ph + (size_t)BATCH * DIM;                   // 4 MB  (needs ws >= 8.375 MB)
  hipMemsetAsync(rk_sum, 0, (size_t)BATCH * SPC * sizeof(float), stream);
  hipMemsetAsync(d_out, 0, sizeof(float), stream);
  k_prep<<<(BATCH * DIM / 4) / 256, 256, 0, stream>>>(preds, Ph, Pl);
  k_group_sims<<<BATCH / SPC, 256, 0, stream>>>(preds, G);
  k_main<<<dim3(BATCH / 128, BATCH / 128), 256, 0, stream>>>(Ph, Pl, G, rk_sum);
  k_fin<<<BATCH / 256, 256, 0, stream>>>(rk_sum, (float*)d_out);
}